// Round 6
// baseline (286.312 us; speedup 1.0000x reference)
//
#include <hip/hip_runtime.h>
#include <math.h>

#define NH   8
#define HD   64
#define BS   4
#define SEQL 2048
#define DIMX 768
#define EMB  512
#define MROWS (BS*SEQL)
#define NSPLIT 4
#define KSPAN (SEQL/NSPLIT)

typedef __attribute__((ext_vector_type(4))) float          f32x4;
typedef __attribute__((ext_vector_type(8))) __bf16         bf16x8;
typedef __attribute__((ext_vector_type(8))) unsigned short u16x8;
typedef __attribute__((ext_vector_type(4))) unsigned short u16x4;

union BF8 { u16x8 u; bf16x8 b; };

__device__ __forceinline__ unsigned short f2bf(float x) {   // RNE
    unsigned int u = __float_as_uint(x);
    u += 0x7FFFu + ((u >> 16) & 1u);
    return (unsigned short)(u >> 16);
}

// pack hi-16s of two floats into one dword: [a.hi16, b.hi16] (truncation)
__device__ __forceinline__ unsigned int pktrunc(float a, float b) {
    return __builtin_amdgcn_perm(__float_as_uint(b), __float_as_uint(a), 0x07060302);
}

#if __has_builtin(__builtin_amdgcn_exp2f)
#define EXP2F(x) __builtin_amdgcn_exp2f(x)
#else
#define EXP2F(x) exp2f(x)
#endif

__device__ __forceinline__ bf16x8 ldb8(const unsigned short* p) {
    return *(const bf16x8*)p;
}

// ---------------------------------------------------------------------------
// All 4 weight transposes in ONE dispatch: fp32 [R][C] -> bf16 [C][R].
// ---------------------------------------------------------------------------
__global__ __launch_bounds__(256)
void transpose_w4(const float* __restrict__ w0, const float* __restrict__ w1,
                  const float* __restrict__ w2, const float* __restrict__ w3,
                  unsigned short* __restrict__ o0, unsigned short* __restrict__ o1,
                  unsigned short* __restrict__ o2, unsigned short* __restrict__ o3)
{
    __shared__ float sm[32][33];
    const int which = blockIdx.y;
    const float* in; unsigned short* out; int R, C;
    if      (which == 0) { in = w0; out = o0; R = DIMX; C = EMB;  }
    else if (which == 1) { in = w1; out = o1; R = DIMX; C = EMB;  }
    else if (which == 2) { in = w2; out = o2; R = DIMX; C = EMB;  }
    else                 { in = w3; out = o3; R = EMB;  C = DIMX; }
    const int nbx = C / 32;
    const int rB = (blockIdx.x / nbx) * 32, cB = (blockIdx.x % nbx) * 32;
    const int row = threadIdx.x >> 3, c4 = (threadIdx.x & 7) * 4;
    f32x4 v = *(const f32x4*)&in[(size_t)(rB + row) * C + cB + c4];
    sm[row][c4 + 0] = v[0]; sm[row][c4 + 1] = v[1];
    sm[row][c4 + 2] = v[2]; sm[row][c4 + 3] = v[3];
    __syncthreads();
    u16x4 o;
    o[0] = f2bf(sm[c4 + 0][row]); o[1] = f2bf(sm[c4 + 1][row]);
    o[2] = f2bf(sm[c4 + 2][row]); o[3] = f2bf(sm[c4 + 3][row]);
    *(u16x4*)&out[(size_t)(cB + row) * R + rB + c4] = o;
}

// ---------------------------------------------------------------------------
// Shared GEMM core: 128x128 tile, BK=64, 256 threads (4 waves as 2x2),
// A[M,K] @ Bt[N,K]^T. LDS padded stride 72 (conflict-free b128).
// AF32: A is fp32, truncate-packed to bf16 via v_perm during staging.
// Software-pipelined: next tile's global loads issue before the MFMA phase,
// so they stay in flight across the barrier (m97 barrier-drain fix).
// DIRECT:  acc[mt][nt] = mfma(x, w)  -> row=m, col=n
// !DIRECT: acc[nt][mt] = mfma(w, x)  -> row=n, col=m  (packed row-major out)
// ---------------------------------------------------------------------------
template<bool DIRECT, bool AF32>
__device__ __forceinline__ void gemm_core(
    const void* __restrict__ Av, const unsigned short* __restrict__ Bt,
    int K, int mBase, int nBase,
    unsigned short* __restrict__ smA, unsigned short* __restrict__ smB,
    f32x4 (&acc)[4][4])
{
    const int tid = threadIdx.x;
    const int lane = tid & 63, w = tid >> 6;
    const int quad = lane >> 4, lanem = lane & 15;
    const int wm = w >> 1, wn = w & 1;
    const int srow = tid >> 3, c8 = (tid & 7) * 8;
    const unsigned short* Ab = (const unsigned short*)Av;
    const float* Af = (const float*)Av;

    const f32x4 z4 = {0.f, 0.f, 0.f, 0.f};
    #pragma unroll
    for (int i = 0; i < 4; ++i)
        #pragma unroll
        for (int j = 0; j < 4; ++j) acc[i][j] = z4;

    auto ldA = [&](int p, int k0) -> u16x8 {
        if constexpr (AF32) {
            const float* bp = &Af[(size_t)(mBase + srow + p * 32) * K + k0 + c8];
            f32x4 x0 = *(const f32x4*)bp;
            f32x4 x1 = *(const f32x4*)(bp + 4);
            union { unsigned int d[4]; u16x8 u; } t;
            t.d[0] = pktrunc(x0[0], x0[1]);
            t.d[1] = pktrunc(x0[2], x0[3]);
            t.d[2] = pktrunc(x1[0], x1[1]);
            t.d[3] = pktrunc(x1[2], x1[3]);
            return t.u;
        } else {
            return *(const u16x8*)&Ab[(size_t)(mBase + srow + p * 32) * K + k0 + c8];
        }
    };
    auto ldB = [&](int p, int k0) -> u16x8 {
        return *(const u16x8*)&Bt[(size_t)(nBase + srow + p * 32) * K + k0 + c8];
    };

    u16x8 va[4], vb[4];
    #pragma unroll
    for (int p = 0; p < 4; ++p) { va[p] = ldA(p, 0); vb[p] = ldB(p, 0); }

    for (int k0 = 0; k0 < K; k0 += 64) {
        __syncthreads();   // guard previous iteration's LDS frag reads
        #pragma unroll
        for (int p = 0; p < 4; ++p) {
            *(u16x8*)&smA[(srow + p * 32) * 72 + c8] = va[p];
            *(u16x8*)&smB[(srow + p * 32) * 72 + c8] = vb[p];
        }
        __syncthreads();
        // prefetch next tile; stays in flight during the MFMA phase
        const int kn = (k0 + 64 < K) ? k0 + 64 : 0;
        #pragma unroll
        for (int p = 0; p < 4; ++p) { va[p] = ldA(p, kn); vb[p] = ldB(p, kn); }

        #pragma unroll
        for (int kk = 0; kk < 64; kk += 32) {
            bf16x8 xa[4], wb[4];
            #pragma unroll
            for (int mt = 0; mt < 4; ++mt)
                xa[mt] = ldb8(&smA[(wm * 64 + mt * 16 + lanem) * 72 + kk + quad * 8]);
            #pragma unroll
            for (int nt = 0; nt < 4; ++nt)
                wb[nt] = ldb8(&smB[(wn * 64 + nt * 16 + lanem) * 72 + kk + quad * 8]);
            if constexpr (DIRECT) {
                #pragma unroll
                for (int mt = 0; mt < 4; ++mt)
                    #pragma unroll
                    for (int nt = 0; nt < 4; ++nt)
                        acc[mt][nt] = __builtin_amdgcn_mfma_f32_16x16x32_bf16(xa[mt], wb[nt], acc[mt][nt], 0, 0, 0);
            } else {
                #pragma unroll
                for (int nt = 0; nt < 4; ++nt)
                    #pragma unroll
                    for (int mt = 0; mt < 4; ++mt)
                        acc[nt][mt] = __builtin_amdgcn_mfma_f32_16x16x32_bf16(wb[nt], xa[mt], acc[nt][mt], 0, 0, 0);
            }
        }
    }
}

// ---------------------------------------------------------------------------
// Fused QKV projection straight from fp32 inputs: grid (4, 64, 3).
// z=0 Q (scaled by (1/8)*log2e), z=1 K, z=2 V -> Vt[b][h][dh][s].
// ---------------------------------------------------------------------------
__global__ __launch_bounds__(256)
void gemm_qkv(const float* __restrict__ query, const float* __restrict__ keyt,
              const float* __restrict__ value, const unsigned short* __restrict__ Wt,
              const float* __restrict__ bq, const float* __restrict__ bk,
              const float* __restrict__ bv,
              unsigned short* __restrict__ Qb, unsigned short* __restrict__ Kb,
              unsigned short* __restrict__ Vtb)
{
    __shared__ unsigned short smA[128 * 72];
    __shared__ unsigned short smB[128 * 72];
    const int z = blockIdx.z;
    const float* A = z == 0 ? query : (z == 1 ? keyt : value);
    const unsigned short* Bt = Wt + (size_t)z * (EMB * DIMX);
    const float* bias = z == 0 ? bq : (z == 1 ? bk : bv);
    const int mBase = blockIdx.y * 128, nBase = blockIdx.x * 128;

    const int tid = threadIdx.x;
    const int lane = tid & 63, w = tid >> 6;
    const int quad = lane >> 4, lanem = lane & 15;
    const int wm = w >> 1, wn = w & 1;

    f32x4 acc[4][4];
    if (z == 2) {
        gemm_core<true, true>(A, Bt, DIMX, mBase, nBase, smA, smB, acc);
        #pragma unroll
        for (int mt = 0; mt < 4; ++mt) {
            const int sg = mBase + wm * 64 + mt * 16 + quad * 4;
            const int b = sg >> 11, s = sg & 2047;
            #pragma unroll
            for (int nt = 0; nt < 4; ++nt) {
                const int de = nBase + wn * 64 + nt * 16 + lanem;
                const float bvv = bias[de];
                const int h = de >> 6, dh = de & 63;
                u16x4 ov;
                #pragma unroll
                for (int r = 0; r < 4; ++r) ov[r] = f2bf(acc[mt][nt][r] + bvv);
                *(u16x4*)&Vtb[((size_t)((b * NH + h) * HD + dh) << 11) + s] = ov;
            }
        }
    } else {
        gemm_core<false, true>(A, Bt, DIMX, mBase, nBase, smA, smB, acc);
        const float os = (z == 0) ? 0.18033688f : 1.0f;   // Q: (1/8)*log2(e)
        unsigned short* C = (z == 0) ? Qb : Kb;
        #pragma unroll
        for (int nt = 0; nt < 4; ++nt) {
            const int n0 = nBase + wn * 64 + nt * 16 + quad * 4;
            const f32x4 b4 = *(const f32x4*)&bias[n0];
            #pragma unroll
            for (int mt = 0; mt < 4; ++mt) {
                const int m = mBase + wm * 64 + mt * 16 + lanem;
                u16x4 ov;
                #pragma unroll
                for (int r = 0; r < 4; ++r) ov[r] = f2bf((acc[nt][mt][r] + b4[r]) * os);
                *(u16x4*)&C[(size_t)m * EMB + n0] = ov;
            }
        }
    }
}

// ---------------------------------------------------------------------------
// Output projection: X[8192,512]bf16 @ Wot[768,512]^T + bo -> fp32 out.
// ---------------------------------------------------------------------------
__global__ __launch_bounds__(256)
void gemm_out(const unsigned short* __restrict__ Xb, const unsigned short* __restrict__ Wot,
              const float* __restrict__ bo, float* __restrict__ out)
{
    __shared__ unsigned short smA[128 * 72];
    __shared__ unsigned short smB[128 * 72];
    const int mBase = blockIdx.y * 128, nBase = blockIdx.x * 128;
    const int tid = threadIdx.x;
    const int lane = tid & 63, w = tid >> 6;
    const int quad = lane >> 4, lanem = lane & 15;
    const int wm = w >> 1, wn = w & 1;

    f32x4 acc[4][4];
    gemm_core<false, false>(Xb, Wot, EMB, mBase, nBase, smA, smB, acc);
    #pragma unroll
    for (int nt = 0; nt < 4; ++nt) {
        const int n0 = nBase + wn * 64 + nt * 16 + quad * 4;
        const f32x4 b4 = *(const f32x4*)&bo[n0];
        #pragma unroll
        for (int mt = 0; mt < 4; ++mt) {
            const int m = mBase + wm * 64 + mt * 16 + lanem;
            f32x4 ov = acc[nt][mt] + b4;
            *(f32x4*)&out[(size_t)m * DIMX + n0] = ov;
        }
    }
}

// ---------------------------------------------------------------------------
// Fused flash attention, LDS-staged, split-K=4, software-pipelined staging.
// Grid 2048 blocks: (bh 32) x (qb 16) x (split 4), XCD-swizzled. 4 waves,
// wave owns 32 q rows. Additive partials (no-max softmax): Opart bf16,
// lpart fp32. S^T = mfma(K,Q); P = exp2, truncated bf16; O^T = mfma(V^T,P);
// l via ones-row MFMA on the same truncated P (bias cancels in O/l).
// ---------------------------------------------------------------------------
__global__ __launch_bounds__(256)
void attn_mfma(const unsigned short* __restrict__ Qb, const unsigned short* __restrict__ Kb,
               const unsigned short* __restrict__ Vt,
               unsigned short* __restrict__ Opart, float* __restrict__ lpart)
{
    __shared__ unsigned short smK[64 * 72];
    __shared__ unsigned short smV[64 * 72];          // V^T tile: [d][k]
    __shared__ unsigned short smP[4][32 * 72];       // per-wave P tile: [q][k]
    const int id = blockIdx.x;
    const int bh = ((id & 7) << 2) | ((id >> 3) & 3);
    const int rest = id >> 5;
    const int qb = rest & 15, sp = rest >> 4;
    const int b = bh >> 3, h = bh & 7;

    const int tid = threadIdx.x;
    const int w = tid >> 6, lane = tid & 63;
    const int quad = lane >> 4, lanem = lane & 15;

    bf16x8 aq[2][2];
    #pragma unroll
    for (int rg = 0; rg < 2; ++rg) {
        const size_t qrow = (size_t)(b * SEQL + qb * 128 + w * 32 + rg * 16 + lanem) * EMB + h * HD;
        aq[rg][0] = ldb8(&Qb[qrow + quad * 8]);
        aq[rg][1] = ldb8(&Qb[qrow + 32 + quad * 8]);
    }

    const f32x4 z4 = {0.f, 0.f, 0.f, 0.f};
    f32x4 o[4][2];
    f32x4 ls[2] = {z4, z4};
    #pragma unroll
    for (int dt = 0; dt < 4; ++dt)
        #pragma unroll
        for (int rg = 0; rg < 2; ++rg) o[dt][rg] = z4;

    BF8 ones;
    #pragma unroll
    for (int i = 0; i < 8; ++i) ones.u[i] = 0x3F80;

    const unsigned short* Kbase = Kb + (size_t)b * SEQL * EMB + h * HD;
    const unsigned short* Vbase = Vt + (size_t)bh * HD * SEQL;
    unsigned short* pW = &smP[w][0];
    const int srow = tid >> 3, c8 = (tid & 7) * 8;

    u16x8 kv[2], vv[2];
    #pragma unroll
    for (int p = 0; p < 2; ++p) {
        kv[p] = *(const u16x8*)&Kbase[(size_t)(sp * KSPAN + srow + p * 32) * EMB + c8];
        vv[p] = *(const u16x8*)&Vbase[(size_t)(srow + p * 32) * SEQL + sp * KSPAN + c8];
    }

    for (int t = 0; t < KSPAN / 64; ++t) {
        __syncthreads();  // previous iteration's frag reads done
        #pragma unroll
        for (int p = 0; p < 2; ++p) {
            *(u16x8*)&smK[(srow + p * 32) * 72 + c8] = kv[p];
            *(u16x8*)&smV[(srow + p * 32) * 72 + c8] = vv[p];
        }
        __syncthreads();
        // prefetch next tile (wraps to span start on last iter; discarded)
        const int k1 = (t + 1 < KSPAN / 64) ? sp * KSPAN + (t + 1) * 64 : sp * KSPAN;
        #pragma unroll
        for (int p = 0; p < 2; ++p) {
            kv[p] = *(const u16x8*)&Kbase[(size_t)(k1 + srow + p * 32) * EMB + c8];
            vv[p] = *(const u16x8*)&Vbase[(size_t)(srow + p * 32) * SEQL + k1 + c8];
        }

        // ---- S^T, exp2, truncated-pack P to LDS ----
        #pragma unroll
        for (int nt = 0; nt < 4; ++nt) {
            bf16x8 bk0 = ldb8(&smK[(nt * 16 + lanem) * 72 + quad * 8]);
            bf16x8 bk1 = ldb8(&smK[(nt * 16 + lanem) * 72 + 32 + quad * 8]);
            #pragma unroll
            for (int rg = 0; rg < 2; ++rg) {
                f32x4 s = __builtin_amdgcn_mfma_f32_16x16x32_bf16(bk0, aq[rg][0], z4, 0, 0, 0);
                s = __builtin_amdgcn_mfma_f32_16x16x32_bf16(bk1, aq[rg][1], s, 0, 0, 0);
                u16x4 pk;
                #pragma unroll
                for (int r = 0; r < 4; ++r)
                    pk[r] = (unsigned short)(__float_as_uint(EXP2F(s[r])) >> 16);
                *(u16x4*)&pW[(rg * 16 + lanem) * 72 + nt * 16 + quad * 4] = pk;
            }
        }
        // ---- P back as B-operand fragments (same wave; no barrier) ----
        bf16x8 pb[2][2];
        #pragma unroll
        for (int rg = 0; rg < 2; ++rg) {
            pb[rg][0] = ldb8(&pW[(rg * 16 + lanem) * 72 + quad * 8]);
            pb[rg][1] = ldb8(&pW[(rg * 16 + lanem) * 72 + 32 + quad * 8]);
        }
        // ---- O^T += V^T @ P^T ; l += ones @ P^T ----
        #pragma unroll
        for (int dt = 0; dt < 4; ++dt) {
            bf16x8 av0 = ldb8(&smV[(dt * 16 + lanem) * 72 + quad * 8]);
            bf16x8 av1 = ldb8(&smV[(dt * 16 + lanem) * 72 + 32 + quad * 8]);
            #pragma unroll
            for (int rg = 0; rg < 2; ++rg) {
                o[dt][rg] = __builtin_amdgcn_mfma_f32_16x16x32_bf16(av0, pb[rg][0], o[dt][rg], 0, 0, 0);
                o[dt][rg] = __builtin_amdgcn_mfma_f32_16x16x32_bf16(av1, pb[rg][1], o[dt][rg], 0, 0, 0);
            }
        }
        #pragma unroll
        for (int rg = 0; rg < 2; ++rg) {
            ls[rg] = __builtin_amdgcn_mfma_f32_16x16x32_bf16(ones.b, pb[rg][0], ls[rg], 0, 0, 0);
            ls[rg] = __builtin_amdgcn_mfma_f32_16x16x32_bf16(ones.b, pb[rg][1], ls[rg], 0, 0, 0);
        }
    }

    // epilogue: bf16 O-partials + fp32 l-partials (additive across splits)
    #pragma unroll
    for (int rg = 0; rg < 2; ++rg) {
        const int qloc = qb * 128 + w * 32 + rg * 16 + lanem;
        unsigned short* orow =
            Opart + ((size_t)sp * 32 * SEQL + (size_t)bh * SEQL + qloc) * HD;
        #pragma unroll
        for (int dt = 0; dt < 4; ++dt) {
            u16x4 ov;
            #pragma unroll
            for (int r = 0; r < 4; ++r) ov[r] = f2bf(o[dt][rg][r]);
            *(u16x4*)&orow[dt * 16 + quad * 4] = ov;
        }
        if (quad == 0)
            lpart[(size_t)sp * 32 * SEQL + (size_t)bh * SEQL + qloc] = ls[rg][0];
    }
}

// ---------------------------------------------------------------------------
// Combine 4 split partials + normalize + cast: Xb[b*S+q][h*64+d] bf16.
// ---------------------------------------------------------------------------
__global__ __launch_bounds__(256)
void attn_reduce(const unsigned short* __restrict__ Opart, const float* __restrict__ lpart,
                 unsigned short* __restrict__ Xb)
{
    const int lin = blockIdx.x * 256 + threadIdx.x;   // 1,048,576 threads
    const int d4 = (lin & 15) << 2;
    const int q = (lin >> 4) & 2047;
    const int bh = lin >> 15;
    const int b = bh >> 3, h = bh & 7;
    const size_t base = ((size_t)bh * SEQL + q) * HD + d4;
    const size_t soff = (size_t)32 * SEQL * HD;
    const size_t lbase = (size_t)bh * SEQL + q;
    const size_t lstr = (size_t)32 * SEQL;
    float acc[4] = {0.f, 0.f, 0.f, 0.f};
    float l = 0.f;
    #pragma unroll
    for (int sp = 0; sp < NSPLIT; ++sp) {
        u16x4 ov = *(const u16x4*)&Opart[base + (size_t)sp * soff];
        #pragma unroll
        for (int r = 0; r < 4; ++r)
            acc[r] += __uint_as_float((unsigned int)ov[r] << 16);
        l += lpart[lbase + (size_t)sp * lstr];
    }
    const float rl = 1.f / l;
    u16x4 xo;
    #pragma unroll
    for (int r = 0; r < 4; ++r) xo[r] = f2bf(acc[r] * rl);
    *(u16x4*)&Xb[((size_t)(b * SEQL + q)) * EMB + h * HD + d4] = xo;
}

// ---------------------------------------------------------------------------
extern "C" void kernel_launch(void* const* d_in, const int* in_sizes, int n_in,
                              void* d_out, int out_size, void* d_ws, size_t ws_size,
                              hipStream_t stream) {
    (void)in_sizes; (void)n_in; (void)out_size; (void)ws_size;
    const float* query = (const float*)d_in[0];
    const float* key   = (const float*)d_in[1];
    const float* value = (const float*)d_in[2];
    const float* wq = (const float*)d_in[3];
    const float* bq = (const float*)d_in[4];
    const float* wk = (const float*)d_in[5];
    const float* bk = (const float*)d_in[6];
    const float* wv = (const float*)d_in[7];
    const float* bv = (const float*)d_in[8];
    const float* wo = (const float*)d_in[9];
    const float* bo = (const float*)d_in[10];
    float* out = (float*)d_out;

    char* ws = (char*)d_ws;
    unsigned short* Opart = (unsigned short*)(ws);              // 33,554,432 B
    float*          lpart = (float*)(ws + 33554432);            //  2,097,152 B
    unsigned short* Wt    = (unsigned short*)(ws + 35651584);   //  2,359,296 B
    unsigned short* Wot   = (unsigned short*)(ws + 38010880);   //    786,432 B
    unsigned short* Qbuf  = (unsigned short*)(ws + 38797312);   //  8,388,608 B
    unsigned short* Xbuf  = Qbuf;                               // alias (Qbuf dead after attn)
    unsigned short* Kbuf  = (unsigned short*)(ws + 47185920);   //  8,388,608 B
    unsigned short* Vtb   = (unsigned short*)(ws + 55574528);   //  8,388,608 B -> ends 63,963,136

    const dim3 blk(256);

    transpose_w4<<<dim3(384, 4), blk, 0, stream>>>(wq, wk, wv, wo,
        Wt, Wt + (size_t)EMB * DIMX, Wt + 2 * (size_t)EMB * DIMX, Wot);

    gemm_qkv<<<dim3(EMB / 128, MROWS / 128, 3), blk, 0, stream>>>(
        query, key, value, Wt, bq, bk, bv, Qbuf, Kbuf, Vtb);

    attn_mfma<<<dim3(32 * 16 * NSPLIT), blk, 0, stream>>>(Qbuf, Kbuf, Vtb, Opart, lpart);
    attn_reduce<<<dim3(4096), blk, 0, stream>>>(Opart, lpart, Xbuf);

    gemm_out<<<dim3(DIMX / 128, MROWS / 128), blk, 0, stream>>>(Xbuf, Wot, bo, out);
}

// Round 7
// 249.911 us; speedup vs baseline: 1.1457x; 1.1457x over previous
//
#include <hip/hip_runtime.h>
#include <math.h>

#define NH   8
#define HD   64
#define BS   4
#define SEQL 2048
#define DIMX 768
#define EMB  512
#define MROWS (BS*SEQL)
#define NSPLIT 4
#define KSPAN (SEQL/NSPLIT)

typedef __attribute__((ext_vector_type(4))) float          f32x4;
typedef __attribute__((ext_vector_type(8))) __bf16         bf16x8;
typedef __attribute__((ext_vector_type(8))) unsigned short u16x8;
typedef __attribute__((ext_vector_type(4))) unsigned short u16x4;

union BF8 { u16x8 u; bf16x8 b; };

__device__ __forceinline__ unsigned short f2bf(float x) {   // RNE
    unsigned int u = __float_as_uint(x);
    u += 0x7FFFu + ((u >> 16) & 1u);
    return (unsigned short)(u >> 16);
}

#if __has_builtin(__builtin_amdgcn_exp2f)
#define EXP2F(x) __builtin_amdgcn_exp2f(x)
#else
#define EXP2F(x) exp2f(x)
#endif

__device__ __forceinline__ bf16x8 ldb8(const unsigned short* p) {
    return *(const bf16x8*)p;
}

// ---------------------------------------------------------------------------
// prep: ONE dispatch doing (a) q/k/v fp32->bf16 RNE cast (also pre-warms L3
// for the projection GEMM's A re-reads) and (b) all 4 weight transposes.
// Grid 4608 blocks: [0,3072) cast (3 tensors x 1024), [3072,4608) weights.
// ---------------------------------------------------------------------------
__global__ __launch_bounds__(256)
void prep(const float* __restrict__ q, const float* __restrict__ k,
          const float* __restrict__ v,
          const float* __restrict__ w0, const float* __restrict__ w1,
          const float* __restrict__ w2, const float* __restrict__ w3,
          unsigned short* __restrict__ castb, unsigned short* __restrict__ Wt,
          unsigned short* __restrict__ Wot)
{
    __shared__ float sm[32][33];
    const int bid = blockIdx.x;
    if (bid < 3072) {
        const int t = bid >> 10;
        const float* src = t == 0 ? q : (t == 1 ? k : v);
        unsigned short* dst = castb + (size_t)t * (MROWS * DIMX);
        int i = ((bid & 1023) << 8) + threadIdx.x;   // f32x4 index
        #pragma unroll
        for (int u = 0; u < 6; ++u, i += 262144) {
            f32x4 x = ((const f32x4*)src)[i];
            u16x4 o;
            o[0] = f2bf(x[0]); o[1] = f2bf(x[1]); o[2] = f2bf(x[2]); o[3] = f2bf(x[3]);
            ((u16x4*)dst)[i] = o;
        }
    } else {
        const int wid = bid - 3072;
        const int which = wid / 384, tile = wid % 384;
        const float* in; unsigned short* out; int R, C;
        if      (which == 0) { in = w0; out = Wt;                           R = DIMX; C = EMB;  }
        else if (which == 1) { in = w1; out = Wt + (size_t)EMB * DIMX;      R = DIMX; C = EMB;  }
        else if (which == 2) { in = w2; out = Wt + 2 * (size_t)EMB * DIMX;  R = DIMX; C = EMB;  }
        else                 { in = w3; out = Wot;                          R = EMB;  C = DIMX; }
        const int nbx = C / 32;
        const int rB = (tile / nbx) * 32, cB = (tile % nbx) * 32;
        const int row = threadIdx.x >> 3, c4 = (threadIdx.x & 7) * 4;
        f32x4 vv = *(const f32x4*)&in[(size_t)(rB + row) * C + cB + c4];
        sm[row][c4 + 0] = vv[0]; sm[row][c4 + 1] = vv[1];
        sm[row][c4 + 2] = vv[2]; sm[row][c4 + 3] = vv[3];
        __syncthreads();
        u16x4 o;
        o[0] = f2bf(sm[c4 + 0][row]); o[1] = f2bf(sm[c4 + 1][row]);
        o[2] = f2bf(sm[c4 + 2][row]); o[3] = f2bf(sm[c4 + 3][row]);
        *(u16x4*)&out[(size_t)(cB + row) * R + rB + c4] = o;
    }
}

// ---------------------------------------------------------------------------
// Shared GEMM core: 128x128 tile, BK=64, 256 threads (4 waves as 2x2),
// bf16 A[M,K] @ Bt[N,K]^T. LDS padded stride 72 (conflict-free b128).
// Software-pipelined: next tile's global loads issue right after the second
// barrier and stay in flight through the MFMA phase; no loads on last iter.
// DIRECT:  acc[mt][nt] = mfma(x, w)  -> row=m, col=n
// !DIRECT: acc[nt][mt] = mfma(w, x)  -> row=n, col=m  (packed row-major out)
// ---------------------------------------------------------------------------
template<bool DIRECT>
__device__ __forceinline__ void gemm_core(
    const unsigned short* __restrict__ A, const unsigned short* __restrict__ Bt,
    int K, int mBase, int nBase,
    unsigned short* __restrict__ smA, unsigned short* __restrict__ smB,
    f32x4 (&acc)[4][4])
{
    const int tid = threadIdx.x;
    const int lane = tid & 63, w = tid >> 6;
    const int quad = lane >> 4, lanem = lane & 15;
    const int wm = w >> 1, wn = w & 1;
    const int srow = tid >> 3, c8 = (tid & 7) * 8;

    const f32x4 z4 = {0.f, 0.f, 0.f, 0.f};
    #pragma unroll
    for (int i = 0; i < 4; ++i)
        #pragma unroll
        for (int j = 0; j < 4; ++j) acc[i][j] = z4;

    u16x8 va[4], vb[4];
    #pragma unroll
    for (int p = 0; p < 4; ++p) {
        va[p] = *(const u16x8*)&A[(size_t)(mBase + srow + p * 32) * K + c8];
        vb[p] = *(const u16x8*)&Bt[(size_t)(nBase + srow + p * 32) * K + c8];
    }

    for (int k0 = 0; k0 < K; k0 += 64) {
        __syncthreads();   // guard previous iteration's LDS frag reads
        #pragma unroll
        for (int p = 0; p < 4; ++p) {
            *(u16x8*)&smA[(srow + p * 32) * 72 + c8] = va[p];
            *(u16x8*)&smB[(srow + p * 32) * 72 + c8] = vb[p];
        }
        __syncthreads();
        if (k0 + 64 < K) {     // prefetch next tile; in flight during MFMA
            const int kn = k0 + 64;
            #pragma unroll
            for (int p = 0; p < 4; ++p) {
                va[p] = *(const u16x8*)&A[(size_t)(mBase + srow + p * 32) * K + kn + c8];
                vb[p] = *(const u16x8*)&Bt[(size_t)(nBase + srow + p * 32) * K + kn + c8];
            }
        }
        #pragma unroll
        for (int kk = 0; kk < 64; kk += 32) {
            bf16x8 xa[4], wb[4];
            #pragma unroll
            for (int mt = 0; mt < 4; ++mt)
                xa[mt] = ldb8(&smA[(wm * 64 + mt * 16 + lanem) * 72 + kk + quad * 8]);
            #pragma unroll
            for (int nt = 0; nt < 4; ++nt)
                wb[nt] = ldb8(&smB[(wn * 64 + nt * 16 + lanem) * 72 + kk + quad * 8]);
            if constexpr (DIRECT) {
                #pragma unroll
                for (int mt = 0; mt < 4; ++mt)
                    #pragma unroll
                    for (int nt = 0; nt < 4; ++nt)
                        acc[mt][nt] = __builtin_amdgcn_mfma_f32_16x16x32_bf16(xa[mt], wb[nt], acc[mt][nt], 0, 0, 0);
            } else {
                #pragma unroll
                for (int nt = 0; nt < 4; ++nt)
                    #pragma unroll
                    for (int mt = 0; mt < 4; ++mt)
                        acc[nt][mt] = __builtin_amdgcn_mfma_f32_16x16x32_bf16(wb[nt], xa[mt], acc[nt][mt], 0, 0, 0);
            }
        }
    }
}

// ---------------------------------------------------------------------------
// Fused QKV projection from bf16 castb: grid (4, 64, 3).
// z=0 Q (scaled by (1/8)*log2e), z=1 K, z=2 V -> Vt[b][h][dh][s].
// ---------------------------------------------------------------------------
__global__ __launch_bounds__(256)
void gemm_qkv(const unsigned short* __restrict__ Xc, const unsigned short* __restrict__ Wt,
              const float* __restrict__ bq, const float* __restrict__ bk,
              const float* __restrict__ bv,
              unsigned short* __restrict__ Qb, unsigned short* __restrict__ Kb,
              unsigned short* __restrict__ Vtb)
{
    __shared__ unsigned short smA[128 * 72];
    __shared__ unsigned short smB[128 * 72];
    const int z = blockIdx.z;
    const unsigned short* A = Xc + (size_t)z * (MROWS * DIMX);
    const unsigned short* Bt = Wt + (size_t)z * (EMB * DIMX);
    const float* bias = z == 0 ? bq : (z == 1 ? bk : bv);
    const int mBase = blockIdx.y * 128, nBase = blockIdx.x * 128;

    const int tid = threadIdx.x;
    const int lane = tid & 63, w = tid >> 6;
    const int quad = lane >> 4, lanem = lane & 15;
    const int wm = w >> 1, wn = w & 1;

    f32x4 acc[4][4];
    if (z == 2) {
        gemm_core<true>(A, Bt, DIMX, mBase, nBase, smA, smB, acc);
        #pragma unroll
        for (int mt = 0; mt < 4; ++mt) {
            const int sg = mBase + wm * 64 + mt * 16 + quad * 4;
            const int b = sg >> 11, s = sg & 2047;
            #pragma unroll
            for (int nt = 0; nt < 4; ++nt) {
                const int de = nBase + wn * 64 + nt * 16 + lanem;
                const float bvv = bias[de];
                const int h = de >> 6, dh = de & 63;
                u16x4 ov;
                #pragma unroll
                for (int r = 0; r < 4; ++r) ov[r] = f2bf(acc[mt][nt][r] + bvv);
                *(u16x4*)&Vtb[((size_t)((b * NH + h) * HD + dh) << 11) + s] = ov;
            }
        }
    } else {
        gemm_core<false>(A, Bt, DIMX, mBase, nBase, smA, smB, acc);
        const float os = (z == 0) ? 0.18033688f : 1.0f;   // Q: (1/8)*log2(e)
        unsigned short* C = (z == 0) ? Qb : Kb;
        #pragma unroll
        for (int nt = 0; nt < 4; ++nt) {
            const int n0 = nBase + wn * 64 + nt * 16 + quad * 4;
            const f32x4 b4 = *(const f32x4*)&bias[n0];
            #pragma unroll
            for (int mt = 0; mt < 4; ++mt) {
                const int m = mBase + wm * 64 + mt * 16 + lanem;
                u16x4 ov;
                #pragma unroll
                for (int r = 0; r < 4; ++r) ov[r] = f2bf((acc[nt][mt][r] + b4[r]) * os);
                *(u16x4*)&C[(size_t)m * EMB + n0] = ov;
            }
        }
    }
}

// ---------------------------------------------------------------------------
// Output projection: X[8192,512]bf16 @ Wot[768,512]^T + bo -> fp32 out.
// ---------------------------------------------------------------------------
__global__ __launch_bounds__(256)
void gemm_out(const unsigned short* __restrict__ Xb, const unsigned short* __restrict__ Wot,
              const float* __restrict__ bo, float* __restrict__ out)
{
    __shared__ unsigned short smA[128 * 72];
    __shared__ unsigned short smB[128 * 72];
    const int mBase = blockIdx.y * 128, nBase = blockIdx.x * 128;
    const int tid = threadIdx.x;
    const int lane = tid & 63, w = tid >> 6;
    const int quad = lane >> 4, lanem = lane & 15;
    const int wm = w >> 1, wn = w & 1;

    f32x4 acc[4][4];
    gemm_core<false>(Xb, Wot, EMB, mBase, nBase, smA, smB, acc);
    #pragma unroll
    for (int nt = 0; nt < 4; ++nt) {
        const int n0 = nBase + wn * 64 + nt * 16 + quad * 4;
        const f32x4 b4 = *(const f32x4*)&bo[n0];
        #pragma unroll
        for (int mt = 0; mt < 4; ++mt) {
            const int m = mBase + wm * 64 + mt * 16 + lanem;
            f32x4 ov = acc[nt][mt] + b4;
            *(f32x4*)&out[(size_t)m * DIMX + n0] = ov;
        }
    }
}

// ---------------------------------------------------------------------------
// Fused flash attention, LDS-staged, split-K=4, software-pipelined staging.
// Grid 2048 blocks: (bh 32) x (qb 16) x (split 4), XCD-swizzled. 4 waves,
// wave owns 32 q rows. Additive partials (no-max softmax): Opart bf16,
// lpart fp32. S^T = mfma(K,Q); P = exp2, truncated bf16; O^T = mfma(V^T,P);
// l via ones-row MFMA on the same truncated P (bias cancels in O/l).
// ---------------------------------------------------------------------------
__global__ __launch_bounds__(256)
void attn_mfma(const unsigned short* __restrict__ Qb, const unsigned short* __restrict__ Kb,
               const unsigned short* __restrict__ Vt,
               unsigned short* __restrict__ Opart, float* __restrict__ lpart)
{
    __shared__ unsigned short smK[64 * 72];
    __shared__ unsigned short smV[64 * 72];          // V^T tile: [d][k]
    __shared__ unsigned short smP[4][32 * 72];       // per-wave P tile: [q][k]
    const int id = blockIdx.x;
    const int bh = ((id & 7) << 2) | ((id >> 3) & 3);
    const int rest = id >> 5;
    const int qb = rest & 15, sp = rest >> 4;
    const int b = bh >> 3, h = bh & 7;

    const int tid = threadIdx.x;
    const int w = tid >> 6, lane = tid & 63;
    const int quad = lane >> 4, lanem = lane & 15;

    bf16x8 aq[2][2];
    #pragma unroll
    for (int rg = 0; rg < 2; ++rg) {
        const size_t qrow = (size_t)(b * SEQL + qb * 128 + w * 32 + rg * 16 + lanem) * EMB + h * HD;
        aq[rg][0] = ldb8(&Qb[qrow + quad * 8]);
        aq[rg][1] = ldb8(&Qb[qrow + 32 + quad * 8]);
    }

    const f32x4 z4 = {0.f, 0.f, 0.f, 0.f};
    f32x4 o[4][2];
    f32x4 ls[2] = {z4, z4};
    #pragma unroll
    for (int dt = 0; dt < 4; ++dt)
        #pragma unroll
        for (int rg = 0; rg < 2; ++rg) o[dt][rg] = z4;

    BF8 ones;
    #pragma unroll
    for (int i = 0; i < 8; ++i) ones.u[i] = 0x3F80;

    const unsigned short* Kbase = Kb + (size_t)b * SEQL * EMB + h * HD;
    const unsigned short* Vbase = Vt + (size_t)bh * HD * SEQL;
    unsigned short* pW = &smP[w][0];
    const int srow = tid >> 3, c8 = (tid & 7) * 8;

    u16x8 kv[2], vv[2];
    #pragma unroll
    for (int p = 0; p < 2; ++p) {
        kv[p] = *(const u16x8*)&Kbase[(size_t)(sp * KSPAN + srow + p * 32) * EMB + c8];
        vv[p] = *(const u16x8*)&Vbase[(size_t)(srow + p * 32) * SEQL + sp * KSPAN + c8];
    }

    for (int t = 0; t < KSPAN / 64; ++t) {
        __syncthreads();  // previous iteration's frag reads done
        #pragma unroll
        for (int p = 0; p < 2; ++p) {
            *(u16x8*)&smK[(srow + p * 32) * 72 + c8] = kv[p];
            *(u16x8*)&smV[(srow + p * 32) * 72 + c8] = vv[p];
        }
        __syncthreads();
        if (t + 1 < KSPAN / 64) {   // prefetch next tile, in flight during MFMA
            const int k1 = sp * KSPAN + (t + 1) * 64;
            #pragma unroll
            for (int p = 0; p < 2; ++p) {
                kv[p] = *(const u16x8*)&Kbase[(size_t)(k1 + srow + p * 32) * EMB + c8];
                vv[p] = *(const u16x8*)&Vbase[(size_t)(srow + p * 32) * SEQL + k1 + c8];
            }
        }

        // ---- S^T, exp2, truncated-pack P to LDS ----
        #pragma unroll
        for (int nt = 0; nt < 4; ++nt) {
            bf16x8 bk0 = ldb8(&smK[(nt * 16 + lanem) * 72 + quad * 8]);
            bf16x8 bk1 = ldb8(&smK[(nt * 16 + lanem) * 72 + 32 + quad * 8]);
            #pragma unroll
            for (int rg = 0; rg < 2; ++rg) {
                f32x4 s = __builtin_amdgcn_mfma_f32_16x16x32_bf16(bk0, aq[rg][0], z4, 0, 0, 0);
                s = __builtin_amdgcn_mfma_f32_16x16x32_bf16(bk1, aq[rg][1], s, 0, 0, 0);
                u16x4 pk;
                #pragma unroll
                for (int r = 0; r < 4; ++r)
                    pk[r] = (unsigned short)(__float_as_uint(EXP2F(s[r])) >> 16);
                *(u16x4*)&pW[(rg * 16 + lanem) * 72 + nt * 16 + quad * 4] = pk;
            }
        }
        // ---- P back as B-operand fragments (same wave; no barrier) ----
        bf16x8 pb[2][2];
        #pragma unroll
        for (int rg = 0; rg < 2; ++rg) {
            pb[rg][0] = ldb8(&pW[(rg * 16 + lanem) * 72 + quad * 8]);
            pb[rg][1] = ldb8(&pW[(rg * 16 + lanem) * 72 + 32 + quad * 8]);
        }
        // ---- O^T += V^T @ P^T ; l += ones @ P^T ----
        #pragma unroll
        for (int dt = 0; dt < 4; ++dt) {
            bf16x8 av0 = ldb8(&smV[(dt * 16 + lanem) * 72 + quad * 8]);
            bf16x8 av1 = ldb8(&smV[(dt * 16 + lanem) * 72 + 32 + quad * 8]);
            #pragma unroll
            for (int rg = 0; rg < 2; ++rg) {
                o[dt][rg] = __builtin_amdgcn_mfma_f32_16x16x32_bf16(av0, pb[rg][0], o[dt][rg], 0, 0, 0);
                o[dt][rg] = __builtin_amdgcn_mfma_f32_16x16x32_bf16(av1, pb[rg][1], o[dt][rg], 0, 0, 0);
            }
        }
        #pragma unroll
        for (int rg = 0; rg < 2; ++rg) {
            ls[rg] = __builtin_amdgcn_mfma_f32_16x16x32_bf16(ones.b, pb[rg][0], ls[rg], 0, 0, 0);
            ls[rg] = __builtin_amdgcn_mfma_f32_16x16x32_bf16(ones.b, pb[rg][1], ls[rg], 0, 0, 0);
        }
    }

    // epilogue: bf16 O-partials + fp32 l-partials (additive across splits)
    #pragma unroll
    for (int rg = 0; rg < 2; ++rg) {
        const int qloc = qb * 128 + w * 32 + rg * 16 + lanem;
        unsigned short* orow =
            Opart + ((size_t)sp * 32 * SEQL + (size_t)bh * SEQL + qloc) * HD;
        #pragma unroll
        for (int dt = 0; dt < 4; ++dt) {
            u16x4 ov;
            #pragma unroll
            for (int r = 0; r < 4; ++r) ov[r] = f2bf(o[dt][rg][r]);
            *(u16x4*)&orow[dt * 16 + quad * 4] = ov;
        }
        if (quad == 0)
            lpart[(size_t)sp * 32 * SEQL + (size_t)bh * SEQL + qloc] = ls[rg][0];
    }
}

// ---------------------------------------------------------------------------
// Combine 4 split partials + normalize + cast: Xb[b*S+q][h*64+d] bf16.
// ---------------------------------------------------------------------------
__global__ __launch_bounds__(256)
void attn_reduce(const unsigned short* __restrict__ Opart, const float* __restrict__ lpart,
                 unsigned short* __restrict__ Xb)
{
    const int lin = blockIdx.x * 256 + threadIdx.x;   // 1,048,576 threads
    const int d4 = (lin & 15) << 2;
    const int q = (lin >> 4) & 2047;
    const int bh = lin >> 15;
    const int b = bh >> 3, h = bh & 7;
    const size_t base = ((size_t)bh * SEQL + q) * HD + d4;
    const size_t soff = (size_t)32 * SEQL * HD;
    const size_t lbase = (size_t)bh * SEQL + q;
    const size_t lstr = (size_t)32 * SEQL;
    float acc[4] = {0.f, 0.f, 0.f, 0.f};
    float l = 0.f;
    #pragma unroll
    for (int sp = 0; sp < NSPLIT; ++sp) {
        u16x4 ov = *(const u16x4*)&Opart[base + (size_t)sp * soff];
        #pragma unroll
        for (int r = 0; r < 4; ++r)
            acc[r] += __uint_as_float((unsigned int)ov[r] << 16);
        l += lpart[lbase + (size_t)sp * lstr];
    }
    const float rl = 1.f / l;
    u16x4 xo;
    #pragma unroll
    for (int r = 0; r < 4; ++r) xo[r] = f2bf(acc[r] * rl);
    *(u16x4*)&Xb[((size_t)(b * SEQL + q)) * EMB + h * HD + d4] = xo;
}

// ---------------------------------------------------------------------------
extern "C" void kernel_launch(void* const* d_in, const int* in_sizes, int n_in,
                              void* d_out, int out_size, void* d_ws, size_t ws_size,
                              hipStream_t stream) {
    (void)in_sizes; (void)n_in; (void)out_size; (void)ws_size;
    const float* query = (const float*)d_in[0];
    const float* key   = (const float*)d_in[1];
    const float* value = (const float*)d_in[2];
    const float* wq = (const float*)d_in[3];
    const float* bq = (const float*)d_in[4];
    const float* wk = (const float*)d_in[5];
    const float* bk = (const float*)d_in[6];
    const float* wv = (const float*)d_in[7];
    const float* bv = (const float*)d_in[8];
    const float* wo = (const float*)d_in[9];
    const float* bo = (const float*)d_in[10];
    float* out = (float*)d_out;

    char* ws = (char*)d_ws;
    // [0, 37.75 MB): castb during projections; Opart+lpart during attention
    // (castb is dead once gemm_qkv completes).
    unsigned short* castb = (unsigned short*)(ws);              // 37,748,736 B
    unsigned short* Opart = (unsigned short*)(ws);              // 33,554,432 B
    float*          lpart = (float*)(ws + 33554432);            //  2,097,152 B
    unsigned short* Wt    = (unsigned short*)(ws + 37748736);   //  2,359,296 B
    unsigned short* Wot   = (unsigned short*)(ws + 40108032);   //    786,432 B
    unsigned short* Qbuf  = (unsigned short*)(ws + 40894464);   //  8,388,608 B
    unsigned short* Xbuf  = Qbuf;                               // alias (Qbuf dead after attn)
    unsigned short* Kbuf  = (unsigned short*)(ws + 49283072);   //  8,388,608 B
    unsigned short* Vtb   = (unsigned short*)(ws + 57671680);   //  8,388,608 B -> ends 66,060,288

    const dim3 blk(256);

    prep<<<dim3(4608), blk, 0, stream>>>(query, key, value, wq, wk, wv, wo,
                                         castb, Wt, Wot);

    gemm_qkv<<<dim3(EMB / 128, MROWS / 128, 3), blk, 0, stream>>>(
        castb, Wt, bq, bk, bv, Qbuf, Kbuf, Vtb);

    attn_mfma<<<dim3(32 * 16 * NSPLIT), blk, 0, stream>>>(Qbuf, Kbuf, Vtb, Opart, lpart);
    attn_reduce<<<dim3(4096), blk, 0, stream>>>(Opart, lpart, Xbuf);

    gemm_out<<<dim3(DIMX / 128, MROWS / 128), blk, 0, stream>>>(Xbuf, Wot, bo, out);
}